// Round 2
// baseline (144.546 us; speedup 1.0000x reference)
//
#include <hip/hip_runtime.h>
#include <hip/hip_bf16.h>
#include <cmath>

#define B_ 64
#define L_ 200
#define H_ 128
#define E_ 256
#define K_ 101

// Dependency-cone DCE: logits read only x[:, L-1, :].  The scan term cancels
// in the inner LayerNorm (h is e-independent -> constant over e), so the
// network is LOCAL in l: only the depthwise conv (k=3, pad 1) couples
// positions, receptive field +-1 per layer.  x[199] therefore depends only on
// x0[197..199].  One block per batch computes a single 16-row tile:
//   layer-0 rows: l = TL0 + i = 186..201  (LN/in_proj tile, M=16)
//   x1 rows     : l = TL1 + r = 187..199  (r = 0..12 valid, LDS fp32)
//   layer-1 rows: l = TL1 + i = 187..200  (i = 0..12 valid)
//   final row   : l = 199 -> final LN -> 101 logits, all in-block.
// v2: single launch.  MFMA B-fragments are gathered straight from the fp32
// weights (8 strided dword loads + cvt per fragment) — no wtrans kernel, no
// workspace, no inter-kernel serialization.  Numerics identical (same
// __float2bfloat16 rounding as the old transpose kernel).
#define TL0 186
#define TL1 187

using short8   = __attribute__((ext_vector_type(8))) short;
using short4_t = __attribute__((ext_vector_type(4))) short;
using f32x4    = __attribute__((ext_vector_type(4))) float;

__device__ __forceinline__ float wave_sum64(float v) {
#pragma unroll
  for (int o = 32; o > 0; o >>= 1) v += __shfl_xor(v, o, 64);
  return v;
}

__device__ __forceinline__ float bf2f(short s) {
  return __uint_as_float(((unsigned)(unsigned short)s) << 16);
}
__device__ __forceinline__ short f2bf(float f) {
  __hip_bfloat16 h = __float2bfloat16(f);
  return *reinterpret_cast<short*>(&h);
}

// B-fragment for mfma_f32_16x16x32_bf16, gathered transposed from a row-major
// fp32 weight W[k][n]: element jj = bf16(W[kbase+jj][col]).
__device__ __forceinline__ short8 ldfragT(const float* __restrict__ W, int ncols,
                                          int col, int kbase) {
  short8 r;
#pragma unroll
  for (int jj = 0; jj < 8; ++jj)
    r[jj] = f2bf(W[(kbase + jj) * ncols + col]);
  return r;
}

// One block per batch b, 512 threads (8 waves, 2 waves/SIMD).  Entire 2-layer
// tail + final LN + logits in a single launch, no global intermediates.
__global__ __launch_bounds__(512, 2) void tail_all_kernel(
    const int* __restrict__ seqs, const int* __restrict__ idxs,
    const float* __restrict__ emb, const float* __restrict__ pos,
    const float* __restrict__ in_w,                                // [2][128][512] fp32
    const float* __restrict__ in_b,                                // [2][512]
    const float* __restrict__ out_w,                               // [2][256][128] fp32
    const float* __restrict__ out_b,                               // [2][128]
    const float* __restrict__ lng, const float* __restrict__ lnb,  // [2][128]
    const float* __restrict__ cw, const float* __restrict__ cb,    // [2][E*3],[2][E]
    const float* __restrict__ D_p, const float* __restrict__ ig,
    const float* __restrict__ ib,                                  // [2][E]
    const float* __restrict__ fg, const float* __restrict__ fb,    // [128]
    float* __restrict__ out) {                                     // [B][K]
  __shared__ __align__(16) short u_s[16][136];   // LN out (bf16); row i <-> l = TB+i
  __shared__ __align__(16) short xz_s[17][520];  // in_proj out; z-half becomes v
  __shared__ __align__(16) float x1_s[16][128];  // layer-0 out (+residual); r <-> l = TL1+r
  __shared__ __align__(16) float xf_s[128];      // final row l=199 (then LN'd in place)

  const int b = blockIdx.x;
  const int tid = threadIdx.x, wid = tid >> 6, lane = tid & 63;
  const int quad = lane >> 4, l16 = lane & 15;

  for (int ly = 0; ly < 2; ++ly) {
    const int TB = ly ? TL1 : TL0;
    const float* wI = in_w + ly * 128 * 512;   // W[k][n], n = 0..511
    const float* wO = out_w + ly * 256 * 128;  // W[e][h], h = 0..127

    // ---- P1/P5: LayerNorm_H -> u_s (bf16).  2 rows per wave, single-pass
    //      mean/var (4 independent shuffle chains interleave). ----
    {
      const float* lg = lng + ly * H_;
      const float* lb = lnb + ly * H_;
      float g0 = lg[lane * 2], g1 = lg[lane * 2 + 1];
      float q0 = lb[lane * 2], q1 = lb[lane * 2 + 1];
      int iA = wid * 2, iB = iA + 1;
      int lA = TB + iA, lB = TB + iB;
      bool vA = (lA < L_), vB = (lB < L_);  // lA,lB >= 186 >= 0 always
      float2 xa, xb;
      if (ly == 0) {
        int lAr = min(lA, L_ - 1), lBr = min(lB, L_ - 1);
        int idA = seqs[b * L_ + lAr], idB = seqs[b * L_ + lBr];
        if (idA != 0) {
          float2 ea = *(const float2*)&emb[(size_t)idA * H_ + lane * 2];
          float2 pa = *(const float2*)&pos[(size_t)lAr * H_ + lane * 2];
          xa = make_float2(ea.x + pa.x, ea.y + pa.y);
        } else xa = make_float2(0.f, 0.f);
        if (idB != 0) {
          float2 eb = *(const float2*)&emb[(size_t)idB * H_ + lane * 2];
          float2 pb = *(const float2*)&pos[(size_t)lBr * H_ + lane * 2];
          xb = make_float2(eb.x + pb.x, eb.y + pb.y);
        } else xb = make_float2(0.f, 0.f);
      } else {
        int rA = min(iA, 12), rB = min(iB, 12);  // x1_s valid rows 0..12
        xa = *(const float2*)&x1_s[rA][lane * 2];
        xb = *(const float2*)&x1_s[rB][lane * 2];
      }
      float sA1 = wave_sum64(xa.x + xa.y);
      float sA2 = wave_sum64(xa.x * xa.x + xa.y * xa.y);
      float sB1 = wave_sum64(xb.x + xb.y);
      float sB2 = wave_sum64(xb.x * xb.x + xb.y * xb.y);
      float mA = sA1 * (1.f / 128.f), mB = sB1 * (1.f / 128.f);
      float vrA = fmaxf(sA2 * (1.f / 128.f) - mA * mA, 0.f);
      float vrB = fmaxf(sB2 * (1.f / 128.f) - mB * mB, 0.f);
      float rA = rsqrtf(vrA + 1e-5f), rB = rsqrtf(vrB + 1e-5f);
      unsigned pA = 0, pB = 0;
      if (vA) {
        pA = ((unsigned)(unsigned short)f2bf((xa.y - mA) * rA * g1 + q1) << 16) |
             (unsigned short)f2bf((xa.x - mA) * rA * g0 + q0);
      }
      if (vB) {
        pB = ((unsigned)(unsigned short)f2bf((xb.y - mB) * rB * g1 + q1) << 16) |
             (unsigned short)f2bf((xb.x - mB) * rB * g0 + q0);
      }
      *(unsigned*)&u_s[iA][lane * 2] = pA;
      *(unsigned*)&u_s[iB][lane * 2] = pB;
    }
    __syncthreads();

    // ---- P2/P6: xz = u @ wI + in_b  (M=16, N=512, K=128).
    //      Wave w owns cols [w*64, w*64+64).  B-frags gathered from fp32. ----
    {
      const float* ibz = in_b + ly * 512;
      short8 afr[4];
#pragma unroll
      for (int kb = 0; kb < 4; ++kb)
        afr[kb] = *(const short8*)&u_s[l16][kb * 32 + quad * 8];
      short8 wb[4][4];  // [sg][kb]; col = wid*64 + sg*16 + l16
#pragma unroll
      for (int sg = 0; sg < 4; ++sg)
#pragma unroll
        for (int kb = 0; kb < 4; ++kb)
          wb[sg][kb] = ldfragT(wI, 512, wid * 64 + sg * 16 + l16,
                               kb * 32 + quad * 8);
      f32x4 acc[4];
#pragma unroll
      for (int sg = 0; sg < 4; ++sg) acc[sg] = f32x4{0.f, 0.f, 0.f, 0.f};
#pragma unroll
      for (int kb = 0; kb < 4; ++kb)
#pragma unroll
        for (int sg = 0; sg < 4; ++sg)
          acc[sg] = __builtin_amdgcn_mfma_f32_16x16x32_bf16(afr[kb], wb[sg][kb],
                                                            acc[sg], 0, 0, 0);
#pragma unroll
      for (int sg = 0; sg < 4; ++sg) {
        int col = wid * 64 + sg * 16 + l16;
        float bz = ibz[col];
#pragma unroll
        for (int r = 0; r < 4; ++r)
          xz_s[quad * 4 + r][col] = f2bf(acc[sg][r] + bz);
      }
    }
    __syncthreads();

    // ---- P3/P7: conv+silu -> y=D*xc -> LN_E (single-pass) -> v=yln*silu(z).
    //      Center row m+1 <-> l = TB+1+m; v overwrites z-half of row m+1
    //      (same-thread read-before-write).  Invalid centers -> 0. ----
    {
      const float* cwl = cw + ly * E_ * 3;
      const float* cbl = cb + ly * E_;
      const float* Dl  = D_p + ly * E_;
      const float* gl  = ig + ly * E_;
      const float* bl  = ib + ly * E_;
      const int e0 = lane * 4;
      float w0[4], w1[4], w2[4], cbv[4], Dv[4], gv[4], bv[4];
#pragma unroll
      for (int j2 = 0; j2 < 4; ++j2) {
        w0[j2] = cwl[(e0 + j2) * 3 + 0];
        w1[j2] = cwl[(e0 + j2) * 3 + 1];
        w2[j2] = cwl[(e0 + j2) * 3 + 2];
        cbv[j2] = cbl[e0 + j2]; Dv[j2] = Dl[e0 + j2];
        gv[j2] = gl[e0 + j2];   bv[j2] = bl[e0 + j2];
      }
#pragma unroll
      for (int j = 0; j < 2; ++j) {
        int m = wid * 2 + j;          // 0..15
        int l = TB + 1 + m;           // center position
        int mr = min(m, 13);          // clamp reads (rows <= 15)
        bool hasL = (l >= 1), hasR = (l + 1 < L_);
        short4_t sm1 = *(const short4_t*)&xz_s[mr][e0];
        short4_t s0  = *(const short4_t*)&xz_s[mr + 1][e0];
        short4_t sp1 = *(const short4_t*)&xz_s[mr + 2][e0];
        short4_t sz  = *(const short4_t*)&xz_s[mr + 1][256 + e0];
        float y[4], p1 = 0.f, p2 = 0.f;
#pragma unroll
        for (int jj = 0; jj < 4; ++jj) {
          float xm1 = hasL ? bf2f(sm1[jj]) : 0.f;
          float x0  = bf2f(s0[jj]);
          float xp1 = hasR ? bf2f(sp1[jj]) : 0.f;
          float cv = w0[jj] * xm1 + w1[jj] * x0 + w2[jj] * xp1 + cbv[jj];
          float sv = cv / (1.f + __expf(-cv));
          y[jj] = Dv[jj] * sv;
          p1 += y[jj]; p2 += y[jj] * y[jj];
        }
        float s1 = wave_sum64(p1), s2 = wave_sum64(p2);
        float mean = s1 * (1.f / 256.f);
        float var = fmaxf(s2 * (1.f / 256.f) - mean * mean, 0.f);
        float rs = rsqrtf(var + 1e-5f);
        short4_t outv;
#pragma unroll
        for (int jj = 0; jj < 4; ++jj) {
          float yln = (y[jj] - mean) * rs * gv[jj] + bv[jj];
          float z = bf2f(sz[jj]);
          outv[jj] = f2bf(yln * (z / (1.f + __expf(-z))));
        }
        if (m > 13 || l < 0 || l >= L_) outv = short4_t{0, 0, 0, 0};
        *(short4_t*)&xz_s[m + 1][256 + e0] = outv;  // v -> z-half of center row
      }
    }
    __syncthreads();

    // ---- P4/P8: out = v @ wO + out_b.  Wave w owns cols [w*16, w*16+16).
    //      Output row r <-> l = TB+1+r.
    //      ly==0: x1 = (x0_embed + out)*mask -> x1_s rows 0..12.
    //      ly==1: only l==199 kept -> xf_s. ----
    {
      const float* obz = out_b + ly * H_;
      short8 vfr[8];
#pragma unroll
      for (int kb = 0; kb < 8; ++kb)
        vfr[kb] = *(const short8*)&xz_s[l16 + 1][256 + kb * 32 + quad * 8];
      int col = wid * 16 + l16;
      short8 wv[8];
#pragma unroll
      for (int kb = 0; kb < 8; ++kb)
        wv[kb] = ldfragT(wO, 128, col, kb * 32 + quad * 8);
      f32x4 acc = {0.f, 0.f, 0.f, 0.f};
#pragma unroll
      for (int kb = 0; kb < 8; ++kb)
        acc = __builtin_amdgcn_mfma_f32_16x16x32_bf16(vfr[kb], wv[kb], acc, 0, 0, 0);
      float bz = obz[col];
      if (ly == 0) {
#pragma unroll
        for (int r = 0; r < 4; ++r) {
          int row = quad * 4 + r;
          int l = TL0 + 1 + row;      // 187 + row
          if (l < L_) {               // row <= 12
            int id = seqs[b * L_ + l];
            float x0 = 0.f;
            if (id != 0)
              x0 = emb[(size_t)id * H_ + col] + pos[(size_t)l * H_ + col];
            x1_s[row][col] = (id != 0) ? (x0 + acc[r] + bz) : 0.f;
          }
        }
      } else {
#pragma unroll
        for (int r = 0; r < 4; ++r) {
          int row = quad * 4 + r;
          int l = TL1 + 1 + row;      // 188 + row
          if (l == L_ - 1) {          // row == 11 (quad 2, r 3)
            int id = seqs[b * L_ + l];
            float xv = x1_s[row + 1][col];  // x1 at l=199
            xf_s[col] = (id != 0) ? (xv + acc[r] + bz) : 0.f;
          }
        }
      }
    }
    __syncthreads();
  }

  // ---- Final LayerNorm of x[b,199] in place (wave 0). ----
  if (wid == 0) {
    float v0 = xf_s[lane * 2], v1 = xf_s[lane * 2 + 1];
    float s1 = wave_sum64(v0 + v1);
    float s2 = wave_sum64(v0 * v0 + v1 * v1);
    float mean = s1 * (1.f / 128.f);
    float var = fmaxf(s2 * (1.f / 128.f) - mean * mean, 0.f);
    float rs = rsqrtf(var + 1e-5f);
    xf_s[lane * 2]     = (v0 - mean) * rs * fg[lane * 2]     + fb[lane * 2];
    xf_s[lane * 2 + 1] = (v1 - mean) * rs * fg[lane * 2 + 1] + fb[lane * 2 + 1];
  }
  __syncthreads();

  // ---- Logits: single round.  4 lanes per item (g = lane&3 owns 32 floats),
  //      128-item capacity >= 101; all gathers in flight together. ----
  {
    int k = wid * 16 + (lane >> 2);
    int g = lane & 3;
    if (k < K_) {
      int id = idxs[b * K_ + k];
      const float* er = &emb[(size_t)id * H_ + g * 32];
      float p = 0.f;
#pragma unroll
      for (int q = 0; q < 8; ++q) {
        float4 e4 = *(const float4*)(er + q * 4);
        float4 x4 = *(const float4*)&xf_s[g * 32 + q * 4];
        p += x4.x * e4.x + x4.y * e4.y + x4.z * e4.z + x4.w * e4.w;
      }
      p += __shfl_xor(p, 1, 64);
      p += __shfl_xor(p, 2, 64);
      if (g == 0) out[b * K_ + k] = p;
    }
  }
}

extern "C" void kernel_launch(void* const* d_in, const int* in_sizes, int n_in,
                              void* d_out, int out_size, void* d_ws, size_t ws_size,
                              hipStream_t stream) {
  const int*   seqs   = (const int*)d_in[0];
  const int*   idxs   = (const int*)d_in[1];
  const float* emb    = (const float*)d_in[2];
  const float* pos    = (const float*)d_in[3];
  const float* blk_g  = (const float*)d_in[4];
  const float* blk_b  = (const float*)d_in[5];
  const float* in_w   = (const float*)d_in[6];
  const float* in_b   = (const float*)d_in[7];
  const float* conv_w = (const float*)d_in[8];
  const float* conv_b = (const float*)d_in[9];
  // d_in[10..12] (xproj_w, xproj_b, A_log) feed only the scan term, which
  // cancels in the inner LayerNorm — unused.
  const float* D_p    = (const float*)d_in[13];
  const float* out_w  = (const float*)d_in[14];
  const float* out_b  = (const float*)d_in[15];
  const float* ig     = (const float*)d_in[16];
  const float* ib     = (const float*)d_in[17];
  const float* fg     = (const float*)d_in[18];
  const float* fb     = (const float*)d_in[19];
  float* out = (float*)d_out;
  (void)d_ws; (void)ws_size;  // no workspace needed

  tail_all_kernel<<<B_, 512, 0, stream>>>(
      seqs, idxs, emb, pos, in_w, in_b, out_w, out_b,
      blk_g, blk_b, conv_w, conv_b, D_p, ig, ib, fg, fb, out);
}

// Round 3
// 141.970 us; speedup vs baseline: 1.0181x; 1.0181x over previous
//
#include <hip/hip_runtime.h>
#include <hip/hip_bf16.h>
#include <cmath>

#define B_ 64
#define L_ 200
#define H_ 128
#define E_ 256
#define K_ 101

// Dependency-cone DCE: logits read only x[:, L-1, :].  The scan term cancels
// in the inner LayerNorm (h is e-independent -> constant over e), so the
// network is LOCAL in l: only the depthwise conv (k=3, pad 1) couples
// positions, receptive field +-1 per layer.  x[199] depends only on
// x0[197..199].  One block per batch computes a single 16-row tile:
//   layer-0 rows: l = TL0 + i = 186..201  (LN/in_proj tile, M=16)
//   x1 rows     : l = TL1 + r = 187..199  (r = 0..12 valid, LDS fp32)
//   layer-1 rows: l = TL1 + i = 187..200  (i = 0..12 valid)
//   final row   : l = 199 -> final LN -> 101 logits, all in-block.
// v3: two kernels (bf16 pre-transposed weights — 16B frag loads, half the
// bytes of inline fp32 gathers; R2 post-mortem) + aggressive cross-phase
// software prefetch in the tail kernel: every global load issued >=1 phase
// before its consuming MFMA/dot, hiding L2 (~200-400cy) and HBM (~900cy)
// latency under the serial phase chain.
#define TL0 186
#define TL1 187

using short8   = __attribute__((ext_vector_type(8))) short;
using short4_t = __attribute__((ext_vector_type(4))) short;
using f32x4    = __attribute__((ext_vector_type(4))) float;

__device__ __forceinline__ float wave_sum64(float v) {
#pragma unroll
  for (int o = 32; o > 0; o >>= 1) v += __shfl_xor(v, o, 64);
  return v;
}

__device__ __forceinline__ float bf2f(short s) {
  return __uint_as_float(((unsigned)(unsigned short)s) << 16);
}
__device__ __forceinline__ short f2bf(float f) {
  __hip_bfloat16 h = __float2bfloat16(f);
  return *reinterpret_cast<short*>(&h);
}

// Combined weight transpose + bf16 cast for both weight tensors (verbatim from
// the verified kernel).
// blocks 0..31:  in_w  [2][128][512] -> wti [2][512][128]
// blocks 32..47: out_w [2][256][128] -> wto [2][128][256]
__global__ void wtrans_kernel(const float* __restrict__ in_w,
                              const float* __restrict__ out_w,
                              __hip_bfloat16* __restrict__ wti,
                              __hip_bfloat16* __restrict__ wto) {
  __shared__ float ts[64][65];
  int bx = blockIdx.x;
  const float* W; __hip_bfloat16* Wt; int K, N, n0, k0;
  if (bx < 32) {
    int blk = bx >> 4, t = bx & 15;
    K = 128; N = 512;
    W = in_w + (size_t)blk * K * N; Wt = wti + (size_t)blk * K * N;
    n0 = (t & 7) * 64; k0 = (t >> 3) * 64;
  } else {
    int b2 = bx - 32, blk = b2 >> 3, t = b2 & 7;
    K = 256; N = 128;
    W = out_w + (size_t)blk * K * N; Wt = wto + (size_t)blk * K * N;
    n0 = (t & 1) * 64; k0 = (t >> 1) * 64;
  }
  int c = threadIdx.x & 63, r4 = threadIdx.x >> 6;
#pragma unroll
  for (int i = 0; i < 16; ++i) {
    int row = r4 * 16 + i;
    ts[row][c] = W[(size_t)(k0 + row) * N + n0 + c];
  }
  __syncthreads();
#pragma unroll
  for (int i = 0; i < 16; ++i) {
    int nrow = r4 * 16 + i;
    Wt[(size_t)(n0 + nrow) * K + k0 + c] = __float2bfloat16(ts[c][nrow]);
  }
}

__device__ __forceinline__ void prefI(short8 wb[4][4], const short* __restrict__ wI,
                                      int wid, int quad, int l16) {
#pragma unroll
  for (int sg = 0; sg < 4; ++sg)
#pragma unroll
    for (int kb = 0; kb < 4; ++kb)
      wb[sg][kb] = *(const short8*)
          &wI[(size_t)(wid * 64 + sg * 16 + l16) * 128 + kb * 32 + quad * 8];
}

__device__ __forceinline__ void prefO(short8 wv[8], const short* __restrict__ wO,
                                      int wid, int quad, int l16) {
  int col = wid * 16 + l16;
#pragma unroll
  for (int kb = 0; kb < 8; ++kb)
    wv[kb] = *(const short8*)&wO[(size_t)col * 256 + kb * 32 + quad * 8];
}

// One block per batch b, 512 threads (8 waves, 2 waves/SIMD).  Entire 2-layer
// tail + final LN + logits; all global loads software-prefetched >=1 phase
// ahead of their consumers.
__global__ __launch_bounds__(512, 2) void tail_fused_kernel(
    const int* __restrict__ seqs, const int* __restrict__ idxs,
    const float* __restrict__ emb, const float* __restrict__ pos,
    const __hip_bfloat16* __restrict__ wti,   // [2][512][128] bf16
    const __hip_bfloat16* __restrict__ wto,   // [2][128][256] bf16
    const float* __restrict__ lng, const float* __restrict__ lnb,  // [2][128]
    const float* __restrict__ in_b,                                // [2][512]
    const float* __restrict__ cw, const float* __restrict__ cb,    // [2][E*3],[2][E]
    const float* __restrict__ D_p, const float* __restrict__ ig,
    const float* __restrict__ ib, const float* __restrict__ out_b, // [2][E]x3,[2][H]
    const float* __restrict__ fg, const float* __restrict__ fb,    // [128]
    float* __restrict__ out) {                                     // [B][K]
  __shared__ __align__(16) short u_s[16][136];   // LN out (bf16); row i <-> l = TB+i
  __shared__ __align__(16) short xz_s[17][520];  // in_proj out; z-half becomes v
  __shared__ __align__(16) float x1_s[16][128];  // layer-0 out (+residual); r <-> l = TL1+r
  __shared__ __align__(16) float xf_s[128];      // final row l=199 (then LN'd in place)

  const int b = blockIdx.x;
  const int tid = threadIdx.x, wid = tid >> 6, lane = tid & 63;
  const int quad = lane >> 4, l16 = lane & 15;
  const short* wtig = (const short*)wti;
  const short* wtog = (const short*)wto;

  // Weight fragments, double-buffered across layers (ly index becomes
  // compile-time constant after the unrolled layer loop -> stays in VGPRs).
  short8 wbI[2][4][4];  // in_proj frags, 64 VGPRs per layer
  short8 wbO[2][8];     // out_proj frags, 32 VGPRs per layer
  // Logits prefetch (issued at P1-ly1; consumed after final LN).
  float4 le[8];
  const int pk = wid * 16 + (lane >> 2);  // 0..127 (item index)
  const int pg = lane & 3;                // 32-float slice owner

  // ---- Prefetch layer-0 in_proj frags before P1 (cover: P1's HBM gathers) ----
  prefI(wbI[0], wtig, wid, quad, l16);

#pragma unroll
  for (int ly = 0; ly < 2; ++ly) {
    const int TB = ly ? TL1 : TL0;

    // ---- P1/P5: LayerNorm_H -> u_s (bf16).  2 rows per wave, single-pass
    //      mean/var (4 independent shuffle chains interleave). ----
    {
      if (ly == 1) {
        // Logits prefetch: idxs + emb rows (HBM); 4 phases of cover.
        int pid = idxs[b * K_ + min(pk, K_ - 1)];
        const float* per = &emb[(size_t)pid * H_ + pg * 32];
#pragma unroll
        for (int q = 0; q < 8; ++q) le[q] = *(const float4*)(per + q * 4);
      }
      const float* lg = lng + ly * H_;
      const float* lb = lnb + ly * H_;
      float g0 = lg[lane * 2], g1 = lg[lane * 2 + 1];
      float q0 = lb[lane * 2], q1 = lb[lane * 2 + 1];
      int iA = wid * 2, iB = iA + 1;
      int lA = TB + iA, lB = TB + iB;
      bool vA = (lA < L_), vB = (lB < L_);  // lA,lB >= 186 >= 0 always
      float2 xa, xb;
      if (ly == 0) {
        int lAr = min(lA, L_ - 1), lBr = min(lB, L_ - 1);
        int idA = seqs[b * L_ + lAr], idB = seqs[b * L_ + lBr];
        if (idA != 0) {
          float2 ea = *(const float2*)&emb[(size_t)idA * H_ + lane * 2];
          float2 pa = *(const float2*)&pos[(size_t)lAr * H_ + lane * 2];
          xa = make_float2(ea.x + pa.x, ea.y + pa.y);
        } else xa = make_float2(0.f, 0.f);
        if (idB != 0) {
          float2 eb = *(const float2*)&emb[(size_t)idB * H_ + lane * 2];
          float2 pb = *(const float2*)&pos[(size_t)lBr * H_ + lane * 2];
          xb = make_float2(eb.x + pb.x, eb.y + pb.y);
        } else xb = make_float2(0.f, 0.f);
      } else {
        int rA = min(iA, 12), rB = min(iB, 12);  // x1_s valid rows 0..12
        xa = *(const float2*)&x1_s[rA][lane * 2];
        xb = *(const float2*)&x1_s[rB][lane * 2];
      }
      float sA1 = wave_sum64(xa.x + xa.y);
      float sA2 = wave_sum64(xa.x * xa.x + xa.y * xa.y);
      float sB1 = wave_sum64(xb.x + xb.y);
      float sB2 = wave_sum64(xb.x * xb.x + xb.y * xb.y);
      float mA = sA1 * (1.f / 128.f), mB = sB1 * (1.f / 128.f);
      float vrA = fmaxf(sA2 * (1.f / 128.f) - mA * mA, 0.f);
      float vrB = fmaxf(sB2 * (1.f / 128.f) - mB * mB, 0.f);
      float rA = rsqrtf(vrA + 1e-5f), rB = rsqrtf(vrB + 1e-5f);
      unsigned pA = 0, pB = 0;
      if (vA) {
        pA = ((unsigned)(unsigned short)f2bf((xa.y - mA) * rA * g1 + q1) << 16) |
             (unsigned short)f2bf((xa.x - mA) * rA * g0 + q0);
      }
      if (vB) {
        pB = ((unsigned)(unsigned short)f2bf((xb.y - mB) * rB * g1 + q1) << 16) |
             (unsigned short)f2bf((xb.x - mB) * rB * g0 + q0);
      }
      *(unsigned*)&u_s[iA][lane * 2] = pA;
      *(unsigned*)&u_s[iB][lane * 2] = pB;
    }
    __syncthreads();

    // ---- P2/P6: xz = u @ wI^T + in_b  (M=16, N=512, K=128).
    //      Wave w owns cols [w*64, w*64+64).  Frags were prefetched. ----
    {
      const float* ibz = in_b + ly * 512;
      short8 afr[4];
#pragma unroll
      for (int kb = 0; kb < 4; ++kb)
        afr[kb] = *(const short8*)&u_s[l16][kb * 32 + quad * 8];
      f32x4 acc[4];
#pragma unroll
      for (int sg = 0; sg < 4; ++sg) acc[sg] = f32x4{0.f, 0.f, 0.f, 0.f};
#pragma unroll
      for (int kb = 0; kb < 4; ++kb)
#pragma unroll
        for (int sg = 0; sg < 4; ++sg)
          acc[sg] = __builtin_amdgcn_mfma_f32_16x16x32_bf16(
              afr[kb], wbI[ly][sg][kb], acc[sg], 0, 0, 0);
      if (ly == 0)  // prefetch layer-1 in_proj frags (cover: P3+P4+P1)
        prefI(wbI[1], wtig + 512 * 128, wid, quad, l16);
#pragma unroll
      for (int sg = 0; sg < 4; ++sg) {
        int col = wid * 64 + sg * 16 + l16;
        float bz = ibz[col];
#pragma unroll
        for (int r = 0; r < 4; ++r)
          xz_s[quad * 4 + r][col] = f2bf(acc[sg][r] + bz);
      }
    }
    __syncthreads();

    // ---- P3/P7: conv+silu -> y=D*xc -> LN_E (single-pass) -> v=yln*silu(z).
    //      Center row m+1 <-> l = TB+1+m; v overwrites z-half of row m+1
    //      (same-thread read-before-write).  Invalid centers -> 0. ----
    {
      if (ly == 0)  // prefetch layer-0 out_proj frags (cover: one phase)
        prefO(wbO[0], wtog, wid, quad, l16);
      const float* cwl = cw + ly * E_ * 3;
      const float* cbl = cb + ly * E_;
      const float* Dl  = D_p + ly * E_;
      const float* gl  = ig + ly * E_;
      const float* bl  = ib + ly * E_;
      const int e0 = lane * 4;
      float w0[4], w1[4], w2[4], cbv[4], Dv[4], gv[4], bv[4];
#pragma unroll
      for (int j2 = 0; j2 < 4; ++j2) {
        w0[j2] = cwl[(e0 + j2) * 3 + 0];
        w1[j2] = cwl[(e0 + j2) * 3 + 1];
        w2[j2] = cwl[(e0 + j2) * 3 + 2];
        cbv[j2] = cbl[e0 + j2]; Dv[j2] = Dl[e0 + j2];
        gv[j2] = gl[e0 + j2];   bv[j2] = bl[e0 + j2];
      }
#pragma unroll
      for (int j = 0; j < 2; ++j) {
        int m = wid * 2 + j;          // 0..15
        int l = TB + 1 + m;           // center position
        int mr = min(m, 13);          // clamp reads (rows <= 15)
        bool hasL = (l >= 1), hasR = (l + 1 < L_);
        short4_t sm1 = *(const short4_t*)&xz_s[mr][e0];
        short4_t s0  = *(const short4_t*)&xz_s[mr + 1][e0];
        short4_t sp1 = *(const short4_t*)&xz_s[mr + 2][e0];
        short4_t sz  = *(const short4_t*)&xz_s[mr + 1][256 + e0];
        float y[4], p1 = 0.f, p2 = 0.f;
#pragma unroll
        for (int jj = 0; jj < 4; ++jj) {
          float xm1 = hasL ? bf2f(sm1[jj]) : 0.f;
          float x0  = bf2f(s0[jj]);
          float xp1 = hasR ? bf2f(sp1[jj]) : 0.f;
          float cv = w0[jj] * xm1 + w1[jj] * x0 + w2[jj] * xp1 + cbv[jj];
          float sv = cv / (1.f + __expf(-cv));
          y[jj] = Dv[jj] * sv;
          p1 += y[jj]; p2 += y[jj] * y[jj];
        }
        float s1 = wave_sum64(p1), s2 = wave_sum64(p2);
        float mean = s1 * (1.f / 256.f);
        float var = fmaxf(s2 * (1.f / 256.f) - mean * mean, 0.f);
        float rs = rsqrtf(var + 1e-5f);
        short4_t outv;
#pragma unroll
        for (int jj = 0; jj < 4; ++jj) {
          float yln = (y[jj] - mean) * rs * gv[jj] + bv[jj];
          float z = bf2f(sz[jj]);
          outv[jj] = f2bf(yln * (z / (1.f + __expf(-z))));
        }
        if (m > 13 || l < 0 || l >= L_) outv = short4_t{0, 0, 0, 0};
        *(short4_t*)&xz_s[m + 1][256 + e0] = outv;  // v -> z-half of center row
      }
    }
    __syncthreads();

    // ---- P4/P8: out = v @ wO^T + out_b.  Wave w owns cols [w*16, w*16+16).
    //      Output row r <-> l = TB+1+r.
    //      ly==0: x1 = (x0_embed + out)*mask -> x1_s rows 0..12.
    //      ly==1: only l==199 kept -> xf_s. ----
    {
      const float* obz = out_b + ly * H_;
      short8 vfr[8];
#pragma unroll
      for (int kb = 0; kb < 8; ++kb)
        vfr[kb] = *(const short8*)&xz_s[l16 + 1][256 + kb * 32 + quad * 8];
      int col = wid * 16 + l16;
      f32x4 acc = {0.f, 0.f, 0.f, 0.f};
#pragma unroll
      for (int kb = 0; kb < 8; ++kb)
        acc = __builtin_amdgcn_mfma_f32_16x16x32_bf16(vfr[kb], wbO[ly][kb],
                                                      acc, 0, 0, 0);
      if (ly == 0)  // prefetch layer-1 out_proj frags (cover: P1+P2+P3)
        prefO(wbO[1], wtog + 128 * 256, wid, quad, l16);
      float bz = obz[col];
      if (ly == 0) {
#pragma unroll
        for (int r = 0; r < 4; ++r) {
          int row = quad * 4 + r;
          int l = TL0 + 1 + row;      // 187 + row
          if (l < L_) {               // row <= 12
            int id = seqs[b * L_ + l];
            float x0 = 0.f;
            if (id != 0)
              x0 = emb[(size_t)id * H_ + col] + pos[(size_t)l * H_ + col];
            x1_s[row][col] = (id != 0) ? (x0 + acc[r] + bz) : 0.f;
          }
        }
      } else {
#pragma unroll
        for (int r = 0; r < 4; ++r) {
          int row = quad * 4 + r;
          int l = TL1 + 1 + row;      // 188 + row
          if (l == L_ - 1) {          // row == 11 (quad 2, r 3)
            int id = seqs[b * L_ + l];
            float xv = x1_s[row + 1][col];  // x1 at l=199
            xf_s[col] = (id != 0) ? (xv + acc[r] + bz) : 0.f;
          }
        }
      }
    }
    __syncthreads();
  }

  // ---- Final LayerNorm of x[b,199] in place (wave 0). ----
  if (wid == 0) {
    float v0 = xf_s[lane * 2], v1 = xf_s[lane * 2 + 1];
    float s1 = wave_sum64(v0 + v1);
    float s2 = wave_sum64(v0 * v0 + v1 * v1);
    float mean = s1 * (1.f / 128.f);
    float var = fmaxf(s2 * (1.f / 128.f) - mean * mean, 0.f);
    float rs = rsqrtf(var + 1e-5f);
    xf_s[lane * 2]     = (v0 - mean) * rs * fg[lane * 2]     + fb[lane * 2];
    xf_s[lane * 2 + 1] = (v1 - mean) * rs * fg[lane * 2 + 1] + fb[lane * 2 + 1];
  }
  __syncthreads();

  // ---- Logits: single round, emb rows already in registers (le).  4 lanes
  //      per item (g = lane&3 owns 32 floats), 2-step shuffle reduce. ----
  if (pk < K_) {
    float p = 0.f;
#pragma unroll
    for (int q = 0; q < 8; ++q) {
      float4 x4 = *(const float4*)&xf_s[pg * 32 + q * 4];
      p += x4.x * le[q].x + x4.y * le[q].y + x4.z * le[q].z + x4.w * le[q].w;
    }
    p += __shfl_xor(p, 1, 64);
    p += __shfl_xor(p, 2, 64);
    if (pg == 0) out[b * K_ + pk] = p;
  }
}

extern "C" void kernel_launch(void* const* d_in, const int* in_sizes, int n_in,
                              void* d_out, int out_size, void* d_ws, size_t ws_size,
                              hipStream_t stream) {
  const int*   seqs   = (const int*)d_in[0];
  const int*   idxs   = (const int*)d_in[1];
  const float* emb    = (const float*)d_in[2];
  const float* pos    = (const float*)d_in[3];
  const float* blk_g  = (const float*)d_in[4];
  const float* blk_b  = (const float*)d_in[5];
  const float* in_w   = (const float*)d_in[6];
  const float* in_b   = (const float*)d_in[7];
  const float* conv_w = (const float*)d_in[8];
  const float* conv_b = (const float*)d_in[9];
  // d_in[10..12] (xproj_w, xproj_b, A_log) feed only the scan term, which
  // cancels in the inner LayerNorm — unused.
  const float* D_p    = (const float*)d_in[13];
  const float* out_w  = (const float*)d_in[14];
  const float* out_b  = (const float*)d_in[15];
  const float* ig     = (const float*)d_in[16];
  const float* ib     = (const float*)d_in[17];
  const float* fg     = (const float*)d_in[18];
  const float* fb     = (const float*)d_in[19];
  float* out = (float*)d_out;
  float* ws = (float*)d_ws;

  // workspace: bf16 weights only (384 KB).  No intermediate activations.
  __hip_bfloat16* wti = (__hip_bfloat16*)ws;            // [2][512][128] bf16 (256 KB)
  __hip_bfloat16* wto = (__hip_bfloat16*)(ws + 65536);  // [2][128][256] bf16 (128 KB)

  wtrans_kernel<<<48, 256, 0, stream>>>(in_w, out_w, wti, wto);

  tail_fused_kernel<<<B_, 512, 0, stream>>>(
      seqs, idxs, emb, pos, wti, wto, blk_g, blk_b, in_b,
      conv_w, conv_b, D_p, ig, ib, out_b, fg, fb, out);
}